// Round 1
// baseline (15062.387 us; speedup 1.0000x reference)
//
#include <hip/hip_runtime.h>
#include <stdint.h>

#define B_ 256
#define S_ 512
#define H_ 256
#define G_ 1024
#define CHUNK 64
#define NCHUNK (S_ / CHUNK)

typedef __attribute__((ext_vector_type(8))) short bf16x8;
typedef __attribute__((ext_vector_type(4))) float f32x4;

__device__ __forceinline__ unsigned short f2bf(float f) {
    unsigned u = __builtin_bit_cast(unsigned, f);
    unsigned r = u + 0x7fffu + ((u >> 16) & 1u);
    return (unsigned short)(r >> 16);
}
__device__ __forceinline__ float bfbits_lo(unsigned v) {  // low 16 bits as bf16 -> f32
    return __builtin_bit_cast(float, (unsigned)(v << 16));
}
__device__ __forceinline__ float bfbits_hi(unsigned v) {
    return __builtin_bit_cast(float, v & 0xffff0000u);
}
__device__ __forceinline__ float sigmoidf_(float x) { return 1.f / (1.f + __expf(-x)); }
__device__ __forceinline__ float tanhf_(float x) { return 2.f / (1.f + __expf(-2.f * x)) - 1.f; }

// ---------------- prep: weights -> fragment-major bf16 ----------------
// Wp[nt][kk][lane][i] = W[k][n], k = kk*32 + (lane>>4)*8 + i, n = nt*16 + (lane&15)
__global__ void prep_w(const float* __restrict__ W, unsigned short* __restrict__ Wp, int NT) {
    int tid = blockIdx.x * 256 + threadIdx.x;
    int total = NT * 8 * 64;
    if (tid >= total) return;
    int l = tid & 63, kk = (tid >> 6) & 7, nt = tid >> 9;
    int n = nt * 16 + (l & 15);
    int k0 = kk * 32 + (l >> 4) * 8;
    int N = NT * 16;
    unsigned short v[8];
#pragma unroll
    for (int i = 0; i < 8; i++) v[i] = f2bf(W[(size_t)(k0 + i) * N + n]);
    uint4 o;
    o.x = (unsigned)v[0] | ((unsigned)v[1] << 16);
    o.y = (unsigned)v[2] | ((unsigned)v[3] << 16);
    o.z = (unsigned)v[4] | ((unsigned)v[5] << 16);
    o.w = (unsigned)v[6] | ((unsigned)v[7] << 16);
    *(uint4*)(Wp + (size_t)tid * 8) = o;
}

__global__ void prep_decay(const float* __restrict__ x, float* __restrict__ dec, int n) {
    int i = blockIdx.x * 256 + threadIdx.x;
    if (i < n) dec[i] = 1.f / logf(2.718281828459045f + x[(size_t)i * H_ + (H_ - 1)]);
}

// ---------------- xg GEMM: [CHUNK*256, 1024] = A[.,256] @ Wx + b ----------------
// Row order: r = t_local*256 + b  (so a 16-row M-tile = 16 consecutive batch rows at one t).
// Output layout (fragment-major): xgp[rowblk][qg 0..63][lane][4 bf16] ; rowblk = t_local*16 + b/16
template <bool SRCF32>
__global__ __launch_bounds__(256) void gemm_xg(const void* __restrict__ src,
                                               const unsigned short* __restrict__ Wp,
                                               const float* __restrict__ bias,
                                               unsigned short* __restrict__ xgp, int chunk) {
    __shared__ short Albs[8 * 8 * 64 * 8];  // 64 KB, frag-major A
    const int tid = threadIdx.x;
    const int bx = blockIdx.x;  // 0..127 M-tile
    const int by = blockIdx.y;  // 0..7  N-block (8 ntiles)
    const int r0 = bx * 128;
    const int t_loc = r0 >> 8;
    const int b0 = r0 & 255;
    const int sg = chunk * CHUNK + t_loc;
    {
        const int m = tid >> 1, kh = tid & 1;
        const size_t rowbase = ((size_t)(b0 + m) * S_ + sg) * H_ + kh * 128;
        if constexpr (SRCF32) {
            const float* p = (const float*)src + rowbase;
#pragma unroll
            for (int jo = 0; jo < 16; jo++) {
                int k = kh * 128 + jo * 8;
                float4 a = *(const float4*)(p + jo * 8);
                float4 b = *(const float4*)(p + jo * 8 + 4);
                int slot = ((m >> 4) * 8 + (k >> 5)) * 64 + ((m & 15) | (((k >> 3) & 3) << 4));
                uint4 o;
                o.x = (unsigned)f2bf(a.x) | ((unsigned)f2bf(a.y) << 16);
                o.y = (unsigned)f2bf(a.z) | ((unsigned)f2bf(a.w) << 16);
                o.z = (unsigned)f2bf(b.x) | ((unsigned)f2bf(b.y) << 16);
                o.w = (unsigned)f2bf(b.z) | ((unsigned)f2bf(b.w) << 16);
                *(uint4*)&Albs[slot * 8] = o;
            }
        } else {
            const unsigned short* p = (const unsigned short*)src + rowbase;
#pragma unroll
            for (int jo = 0; jo < 16; jo++) {
                int k = kh * 128 + jo * 8;
                uint4 o = *(const uint4*)(p + jo * 8);
                int slot = ((m >> 4) * 8 + (k >> 5)) * 64 + ((m & 15) | (((k >> 3) & 3) << 4));
                *(uint4*)&Albs[slot * 8] = o;
            }
        }
    }
    __syncthreads();
    const int w = tid >> 6, l = tid & 63;
    const int wm = w >> 1, wn = w & 1;
    const int col = l & 15;
    float bv[4];
#pragma unroll
    for (int q = 0; q < 4; q++) bv[q] = bias[(by * 8 + wn * 4 + q) * 16 + col];
    f32x4 acc[4][4];
#pragma unroll
    for (int mi = 0; mi < 4; mi++)
#pragma unroll
        for (int q = 0; q < 4; q++) {
            acc[mi][q][0] = bv[q]; acc[mi][q][1] = bv[q];
            acc[mi][q][2] = bv[q]; acc[mi][q][3] = bv[q];
        }
    const bf16x8* Wp8 = (const bf16x8*)Wp;
#pragma unroll
    for (int kk = 0; kk < 8; kk++) {
        bf16x8 af[4], bfr[4];
#pragma unroll
        for (int mi = 0; mi < 4; mi++)
            af[mi] = *(const bf16x8*)&Albs[(((wm * 4 + mi) * 8 + kk) * 64 + l) * 8];
#pragma unroll
        for (int q = 0; q < 4; q++)
            bfr[q] = Wp8[((size_t)(by * 8 + wn * 4 + q) * 8 + kk) * 64 + l];
#pragma unroll
        for (int mi = 0; mi < 4; mi++)
#pragma unroll
            for (int q = 0; q < 4; q++)
                acc[mi][q] = __builtin_amdgcn_mfma_f32_16x16x32_bf16(af[mi], bfr[q], acc[mi][q], 0, 0, 0);
    }
    const int rblk0 = r0 >> 4;
#pragma unroll
    for (int mi = 0; mi < 4; mi++) {
        int rowblk = rblk0 + wm * 4 + mi;
#pragma unroll
        for (int q = 0; q < 4; q++) {
            int qg = by * 8 + wn * 4 + q;
            uint2 o;
            o.x = (unsigned)f2bf(acc[mi][q][0]) | ((unsigned)f2bf(acc[mi][q][1]) << 16);
            o.y = (unsigned)f2bf(acc[mi][q][2]) | ((unsigned)f2bf(acc[mi][q][3]) << 16);
            *(uint2*)&xgp[(((size_t)rowblk * 64 + qg) * 64 + l) * 4] = o;
        }
    }
}

// ---------------- persistent scan kernel ----------------
// 16 WGs x 512 threads (8 waves). WG = 16 batch rows. Wave w owns col-blocks {w, w+8}.
template <bool L0>
__global__ __launch_bounds__(512) void rec_step(const unsigned short* __restrict__ xgp,
                                                const unsigned short* __restrict__ Whp,
                                                const unsigned short* __restrict__ Wdp,
                                                const float* __restrict__ bd,
                                                const float* __restrict__ dec_in,
                                                void* __restrict__ yout,
                                                float* __restrict__ dec_out,
                                                float* __restrict__ h_state,
                                                float* __restrict__ c_state, int chunk) {
    __shared__ short hbf[16 * 256];
    __shared__ short cbf[16 * 256];
    const int tid = threadIdx.x;
    const int w = tid >> 6, l = tid & 63;
    const int lgrp = l >> 4, col = l & 15;
    const int bblk = blockIdx.x;
    const int b0 = bblk * 16;
    const int cb[2] = {w, w + 8};
    float bdv[2];
#pragma unroll
    for (int j = 0; j < 2; j++) bdv[j] = bd[cb[j] * 16 + col];
    float creg[2][4], hreg[2][4];
    if (chunk == 0) {
        for (int i = tid; i < 4096; i += 512) { hbf[i] = 0; cbf[i] = 0; }
#pragma unroll
        for (int j = 0; j < 2; j++)
#pragma unroll
            for (int r = 0; r < 4; r++) { creg[j][r] = 0.f; hreg[j][r] = 0.f; }
    } else {
#pragma unroll
        for (int j = 0; j < 2; j++)
#pragma unroll
            for (int r = 0; r < 4; r++) {
                int row = lgrp * 4 + r;
                int n = cb[j] * 16 + col;
                float cv = c_state[(size_t)(b0 + row) * H_ + n];
                float hv = h_state[(size_t)(b0 + row) * H_ + n];
                creg[j][r] = cv; hreg[j][r] = hv;
                hbf[row * 256 + (n ^ ((row & 7) << 3))] = (short)f2bf(hv);
                cbf[row * 256 + (n ^ ((row & 7) << 3))] = (short)f2bf(cv);
            }
    }
    __syncthreads();
    const bf16x8* Whp8 = (const bf16x8*)Whp;
    const bf16x8* Wdp8 = (const bf16x8*)Wdp;
    const uint2* xg8 = (const uint2*)xgp;

#pragma unroll 1
    for (int t = 0; t < CHUNK; ++t) {
        const int tg = chunk * CHUNK + t;
        const int rowblk = t * 16 + bblk;
        uint2 xgv[2][4];
#pragma unroll
        for (int j = 0; j < 2; j++)
#pragma unroll
            for (int q = 0; q < 4; q++) {
                int qg = q * 16 + cb[j];
                xgv[j][q] = xg8[((size_t)rowblk * 64 + qg) * 64 + l];
            }
        float dec[4];
#pragma unroll
        for (int r = 0; r < 4; r++) dec[r] = dec_in[(size_t)(b0 + lgrp * 4 + r) * S_ + tg];
        // cs = c @ Wd
        f32x4 csacc[2];
#pragma unroll
        for (int j = 0; j < 2; j++) { csacc[j][0] = 0.f; csacc[j][1] = 0.f; csacc[j][2] = 0.f; csacc[j][3] = 0.f; }
#pragma unroll
        for (int kk = 0; kk < 8; kk++) {
            bf16x8 cf = *(const bf16x8*)&cbf[col * 256 + ((kk * 32 + lgrp * 8) ^ ((col & 7) << 3))];
#pragma unroll
            for (int j = 0; j < 2; j++)
                csacc[j] = __builtin_amdgcn_mfma_f32_16x16x32_bf16(cf, Wdp8[(cb[j] * 8 + kk) * 64 + l], csacc[j], 0, 0, 0);
        }
        // g = xg + h @ Wh
        f32x4 gacc[2][4];
#pragma unroll
        for (int j = 0; j < 2; j++)
#pragma unroll
            for (int q = 0; q < 4; q++) {
                uint2 v = xgv[j][q];
                gacc[j][q][0] = bfbits_lo(v.x);
                gacc[j][q][1] = bfbits_hi(v.x);
                gacc[j][q][2] = bfbits_lo(v.y);
                gacc[j][q][3] = bfbits_hi(v.y);
            }
#pragma unroll
        for (int kk = 0; kk < 8; kk++) {
            bf16x8 hf = *(const bf16x8*)&hbf[col * 256 + ((kk * 32 + lgrp * 8) ^ ((col & 7) << 3))];
#pragma unroll
            for (int j = 0; j < 2; j++)
#pragma unroll
                for (int q = 0; q < 4; q++)
                    gacc[j][q] = __builtin_amdgcn_mfma_f32_16x16x32_bf16(hf, Whp8[((q * 16 + cb[j]) * 8 + kk) * 64 + l], gacc[j][q], 0, 0, 0);
        }
        __syncthreads();  // all reads of hbf/cbf done
#pragma unroll
        for (int j = 0; j < 2; j++) {
#pragma unroll
            for (int r = 0; r < 4; r++) {
                int row = lgrp * 4 + r;
                float cs = tanhf_(csacc[j][r] + bdv[j]);
                float cadj = creg[j][r] - cs + cs * dec[r];
                float iv = sigmoidf_(gacc[j][0][r]);
                float fv = sigmoidf_(gacc[j][1][r]);
                float ov = sigmoidf_(gacc[j][2][r]);
                float cd = tanhf_(gacc[j][3][r]);
                float cn = fv * cadj + iv * cd;
                float hn = ov * tanhf_(cn);
                creg[j][r] = cn; hreg[j][r] = hn;
                int n = cb[j] * 16 + col;
                hbf[row * 256 + (n ^ ((row & 7) << 3))] = (short)f2bf(hn);
                cbf[row * 256 + (n ^ ((row & 7) << 3))] = (short)f2bf(cn);
                size_t yi = ((size_t)(b0 + row) * S_ + tg) * H_ + n;
                if (L0) {
                    ((unsigned short*)yout)[yi] = f2bf(hn);
                    if (n == H_ - 1) dec_out[(size_t)(b0 + row) * S_ + tg] = 1.f / logf(2.718281828459045f + hn);
                } else {
                    ((float*)yout)[yi] = hn;
                }
            }
        }
        __syncthreads();  // new hbf/cbf visible
    }
#pragma unroll
    for (int j = 0; j < 2; j++)
#pragma unroll
        for (int r = 0; r < 4; r++) {
            int row = lgrp * 4 + r, n = cb[j] * 16 + col;
            h_state[(size_t)(b0 + row) * H_ + n] = hreg[j][r];
            c_state[(size_t)(b0 + row) * H_ + n] = creg[j][r];
        }
}

__global__ void copy_tail(const float* __restrict__ a, const float* __restrict__ b,
                          const float* __restrict__ c, const float* __restrict__ d,
                          float* __restrict__ out) {
    int i = blockIdx.x * 256 + threadIdx.x;
    if (i >= 4 * 65536) return;
    const float* src = (i >> 16) == 0 ? a : (i >> 16) == 1 ? b : (i >> 16) == 2 ? c : d;
    out[i] = src[i & 65535];
}

extern "C" void kernel_launch(void* const* d_in, const int* in_sizes, int n_in, void* d_out,
                              int out_size, void* d_ws, size_t ws_size, hipStream_t stream) {
    (void)in_sizes; (void)n_in; (void)out_size; (void)ws_size;
    const float* x   = (const float*)d_in[0];
    const float* Wx0 = (const float*)d_in[1];
    const float* Wh0 = (const float*)d_in[2];
    const float* b0  = (const float*)d_in[3];
    const float* Wd0 = (const float*)d_in[4];
    const float* bd0 = (const float*)d_in[5];
    const float* Wx1 = (const float*)d_in[6];
    const float* Wh1 = (const float*)d_in[7];
    const float* b1  = (const float*)d_in[8];
    const float* Wd1 = (const float*)d_in[9];
    const float* bd1 = (const float*)d_in[10];

    char* ws = (char*)d_ws;
    size_t off = 0;
    auto take = [&](size_t bytes) { void* p = ws + off; off += (bytes + 255) & ~(size_t)255; return p; };
    unsigned short* wxp0 = (unsigned short*)take(524288);
    unsigned short* whp0 = (unsigned short*)take(524288);
    unsigned short* wdp0 = (unsigned short*)take(131072);
    unsigned short* wxp1 = (unsigned short*)take(524288);
    unsigned short* whp1 = (unsigned short*)take(524288);
    unsigned short* wdp1 = (unsigned short*)take(131072);
    float* dec0 = (float*)take(524288);
    float* dec1 = (float*)take(524288);
    float* hs0 = (float*)take(262144);
    float* cs0 = (float*)take(262144);
    float* hs1 = (float*)take(262144);
    float* cs1 = (float*)take(262144);
    unsigned short* y0bf = (unsigned short*)take(67108864);
    unsigned short* xgp  = (unsigned short*)take(33554432);

    prep_w<<<128, 256, 0, stream>>>(Wx0, wxp0, 64);
    prep_w<<<128, 256, 0, stream>>>(Wh0, whp0, 64);
    prep_w<<<32, 256, 0, stream>>>(Wd0, wdp0, 16);
    prep_w<<<128, 256, 0, stream>>>(Wx1, wxp1, 64);
    prep_w<<<128, 256, 0, stream>>>(Wh1, whp1, 64);
    prep_w<<<32, 256, 0, stream>>>(Wd1, wdp1, 16);
    prep_decay<<<512, 256, 0, stream>>>(x, dec0, B_ * S_);

    dim3 ggrid(128, 8);
    for (int c = 0; c < NCHUNK; ++c) {
        gemm_xg<true><<<ggrid, 256, 0, stream>>>(x, wxp0, b0, xgp, c);
        rec_step<true><<<16, 512, 0, stream>>>(xgp, whp0, wdp0, bd0, dec0, y0bf, dec1, hs0, cs0, c);
    }
    float* y1 = (float*)d_out;
    for (int c = 0; c < NCHUNK; ++c) {
        gemm_xg<false><<<ggrid, 256, 0, stream>>>(y0bf, wxp1, b1, xgp, c);
        rec_step<false><<<16, 512, 0, stream>>>(xgp, whp1, wdp1, bd1, dec1, y1, nullptr, hs1, cs1, c);
    }
    copy_tail<<<1024, 256, 0, stream>>>(hs0, cs0, hs1, cs1, (float*)d_out + (size_t)B_ * S_ * H_);
}

// Round 2
// 9283.273 us; speedup vs baseline: 1.6225x; 1.6225x over previous
//
#include <hip/hip_runtime.h>
#include <stdint.h>

#define B_ 256
#define S_ 512
#define H_ 256
#define G_ 1024
#define CHUNK 32
#define NCHUNK (S_ / CHUNK)

typedef __attribute__((ext_vector_type(8))) short bf16x8;
typedef __attribute__((ext_vector_type(4))) float f32x4;

__device__ __forceinline__ unsigned short f2bf(float f) {
    unsigned u = __builtin_bit_cast(unsigned, f);
    unsigned r = u + 0x7fffu + ((u >> 16) & 1u);
    return (unsigned short)(r >> 16);
}
__device__ __forceinline__ float bf2f(unsigned short v) {
    return __builtin_bit_cast(float, (unsigned)v << 16);
}
__device__ __forceinline__ float bfbits_lo(unsigned v) {
    return __builtin_bit_cast(float, (unsigned)(v << 16));
}
__device__ __forceinline__ float bfbits_hi(unsigned v) {
    return __builtin_bit_cast(float, v & 0xffff0000u);
}
__device__ __forceinline__ float sigmoidf_(float x) { return 1.f / (1.f + __expf(-x)); }
__device__ __forceinline__ float tanhf_(float x) { return 2.f / (1.f + __expf(-2.f * x)) - 1.f; }

// ---------------- prep: weights -> fragment-major bf16 ----------------
// Wp[nt][kk][lane][i] = W[k][n], k = kk*32 + (lane>>4)*8 + i, n = nt*16 + (lane&15)
__global__ void prep_w(const float* __restrict__ W, unsigned short* __restrict__ Wp, int NT) {
    int tid = blockIdx.x * 256 + threadIdx.x;
    int total = NT * 8 * 64;
    if (tid >= total) return;
    int l = tid & 63, kk = (tid >> 6) & 7, nt = tid >> 9;
    int n = nt * 16 + (l & 15);
    int k0 = kk * 32 + (l >> 4) * 8;
    int N = NT * 16;
    unsigned short v[8];
#pragma unroll
    for (int i = 0; i < 8; i++) v[i] = f2bf(W[(size_t)(k0 + i) * N + n]);
    uint4 o;
    o.x = (unsigned)v[0] | ((unsigned)v[1] << 16);
    o.y = (unsigned)v[2] | ((unsigned)v[3] << 16);
    o.z = (unsigned)v[4] | ((unsigned)v[5] << 16);
    o.w = (unsigned)v[6] | ((unsigned)v[7] << 16);
    *(uint4*)(Wp + (size_t)tid * 8) = o;
}

__global__ void prep_decay(const float* __restrict__ x, float* __restrict__ dec, int n) {
    int i = blockIdx.x * 256 + threadIdx.x;
    if (i < n) dec[i] = 1.f / __logf(2.718281828459045f + x[(size_t)i * H_ + (H_ - 1)]);
}

// ---------------- xg GEMM body ----------------
// Output layout (fragment-major): xgp[rowblk][qg 0..63][lane][4 bf16], rowblk = t_local*16 + b/16
template <bool SRCF32>
__device__ void gemm_body(const void* __restrict__ src, const unsigned short* __restrict__ Wp,
                          const float* __restrict__ bias, unsigned short* __restrict__ xgp,
                          int chunk, short* Albs) {
    const int tid = threadIdx.x;
    const int bx = blockIdx.x;  // 0..63 M-tile (128 rows)
    const int by = blockIdx.y;  // 0..7  N-block
    const int r0 = bx * 128;
    const int t_loc = r0 >> 8;
    const int b0 = r0 & 255;
    const int sg = chunk * CHUNK + t_loc;
    {
        const int m = tid >> 1, kh = tid & 1;
        const size_t rowbase = ((size_t)(b0 + m) * S_ + sg) * H_ + kh * 128;
        if constexpr (SRCF32) {
            const float* p = (const float*)src + rowbase;
#pragma unroll
            for (int jo = 0; jo < 16; jo++) {
                int k = kh * 128 + jo * 8;
                float4 a = *(const float4*)(p + jo * 8);
                float4 b = *(const float4*)(p + jo * 8 + 4);
                int slot = ((m >> 4) * 8 + (k >> 5)) * 64 + ((m & 15) | (((k >> 3) & 3) << 4));
                uint4 o;
                o.x = (unsigned)f2bf(a.x) | ((unsigned)f2bf(a.y) << 16);
                o.y = (unsigned)f2bf(a.z) | ((unsigned)f2bf(a.w) << 16);
                o.z = (unsigned)f2bf(b.x) | ((unsigned)f2bf(b.y) << 16);
                o.w = (unsigned)f2bf(b.z) | ((unsigned)f2bf(b.w) << 16);
                *(uint4*)&Albs[slot * 8] = o;
            }
        } else {
            const unsigned short* p = (const unsigned short*)src + rowbase;
#pragma unroll
            for (int jo = 0; jo < 16; jo++) {
                int k = kh * 128 + jo * 8;
                uint4 o = *(const uint4*)(p + jo * 8);
                int slot = ((m >> 4) * 8 + (k >> 5)) * 64 + ((m & 15) | (((k >> 3) & 3) << 4));
                *(uint4*)&Albs[slot * 8] = o;
            }
        }
    }
    __syncthreads();
    const int w = tid >> 6, l = tid & 63;
    const int wm = w >> 1, wn = w & 1;
    const int col = l & 15;
    float bv[4];
#pragma unroll
    for (int q = 0; q < 4; q++) bv[q] = bias[(by * 8 + wn * 4 + q) * 16 + col];
    f32x4 acc[4][4];
#pragma unroll
    for (int mi = 0; mi < 4; mi++)
#pragma unroll
        for (int q = 0; q < 4; q++) {
            acc[mi][q][0] = bv[q]; acc[mi][q][1] = bv[q];
            acc[mi][q][2] = bv[q]; acc[mi][q][3] = bv[q];
        }
    const bf16x8* Wp8 = (const bf16x8*)Wp;
#pragma unroll
    for (int kk = 0; kk < 8; kk++) {
        bf16x8 af[4], bfr[4];
#pragma unroll
        for (int mi = 0; mi < 4; mi++)
            af[mi] = *(const bf16x8*)&Albs[(((wm * 4 + mi) * 8 + kk) * 64 + l) * 8];
#pragma unroll
        for (int q = 0; q < 4; q++)
            bfr[q] = Wp8[((size_t)(by * 8 + wn * 4 + q) * 8 + kk) * 64 + l];
#pragma unroll
        for (int mi = 0; mi < 4; mi++)
#pragma unroll
            for (int q = 0; q < 4; q++)
                acc[mi][q] = __builtin_amdgcn_mfma_f32_16x16x32_bf16(af[mi], bfr[q], acc[mi][q], 0, 0, 0);
    }
    const int rblk0 = r0 >> 4;
#pragma unroll
    for (int mi = 0; mi < 4; mi++) {
        int rowblk = rblk0 + wm * 4 + mi;
#pragma unroll
        for (int q = 0; q < 4; q++) {
            int qg = by * 8 + wn * 4 + q;
            uint2 o;
            o.x = (unsigned)f2bf(acc[mi][q][0]) | ((unsigned)f2bf(acc[mi][q][1]) << 16);
            o.y = (unsigned)f2bf(acc[mi][q][2]) | ((unsigned)f2bf(acc[mi][q][3]) << 16);
            *(uint2*)&xgp[(((size_t)rowblk * 64 + qg) * 64 + l) * 4] = o;
        }
    }
}

// dual-layer GEMM: z=0 -> layer0 chunk c0 (f32 src x), z=1 -> layer1 chunk c1 (bf16 src y0)
__global__ __launch_bounds__(256) void gemm_dual(const float* __restrict__ x,
                                                 const unsigned short* __restrict__ y0bf,
                                                 const unsigned short* __restrict__ Wp0,
                                                 const float* __restrict__ bias0,
                                                 const unsigned short* __restrict__ Wp1,
                                                 const float* __restrict__ bias1,
                                                 unsigned short* __restrict__ xgpA,
                                                 unsigned short* __restrict__ xgpB, int c0, int c1) {
    extern __shared__ short Albs[];  // 64 KB
    if (blockIdx.z == 0) {
        if (c0 < 0) return;
        gemm_body<true>(x, Wp0, bias0, xgpA, c0, Albs);
    } else {
        if (c1 < 0) return;
        gemm_body<false>(y0bf, Wp1, bias1, xgpB, c1, Albs);
    }
}

// ---------------- recurrent scan: 16 WGs/layer x 1024 threads (16 waves) ----------------
// Wave w owns gate n-tiles {q*16+w, q=0..3} and cs n-tile w. WG = 16 batch rows.
template <bool ISL0>
__device__ void rec_run(const unsigned short* __restrict__ xgp, const bf16x8* __restrict__ Whp8,
                        const bf16x8* __restrict__ Wdp8, const float* __restrict__ bd,
                        const float* __restrict__ dec_in, void* __restrict__ yout,
                        float* __restrict__ dec_out, unsigned short* __restrict__ h_state,
                        float* __restrict__ c_state, int chunk, int bblk, char* smem) {
    short* hb = (short*)smem;                          // [2][16][256]
    short* cb = (short*)(smem + 2 * 4096 * 2);         // [2][16][256]
    float* decs = (float*)(smem + 4 * 4096 * 2);       // [CHUNK][17]
    const int tid = threadIdx.x;
    const int w = tid >> 6, l = tid & 63;
    const int lgrp = l >> 4, col = l & 15;
    const int b0 = bblk * 16;
    const int n = w * 16 + col;
    const float bdv = bd[n];

    if (tid < 16 * CHUNK) {  // stage decay for this chunk, coalesced
        int row = tid >> 5, t = tid & (CHUNK - 1);
        decs[t * 17 + row] = dec_in[(size_t)(b0 + row) * S_ + chunk * CHUNK + t];
    }
    bf16x8 wd[8];  // Wd tile w resident in registers for the whole chunk
#pragma unroll
    for (int kk = 0; kk < 8; kk++) wd[kk] = Wdp8[((size_t)w * 8 + kk) * 64 + l];

    float creg[4];
    if (chunk == 0) {
#pragma unroll
        for (int r = 0; r < 4; r++) creg[r] = 0.f;
        for (int i = tid; i < 4096; i += 1024) { hb[i] = 0; cb[i] = 0; }
    } else {
#pragma unroll
        for (int r = 0; r < 4; r++) {
            int row = lgrp * 4 + r;
            float cv = c_state[(size_t)(b0 + row) * H_ + n];
            creg[r] = cv;
            unsigned short hv = h_state[(size_t)(b0 + row) * H_ + n];
            int sw = n ^ ((row & 7) << 3);
            hb[row * 256 + sw] = (short)hv;
            cb[row * 256 + sw] = (short)f2bf(cv);
        }
    }
    __syncthreads();

    const uint2* xg8 = (const uint2*)xgp;
    uint2 xc[4], xn[4];
#pragma unroll
    for (int q = 0; q < 4; q++)
        xc[q] = xg8[((size_t)(0 * 16 + bblk) * 64 + (q * 16 + w)) * 64 + l];
    int cur = 0;

#pragma unroll 1
    for (int t = 0; t < CHUNK; ++t) {
        const int tg = chunk * CHUNK + t;
        if (t + 1 < CHUNK) {  // prefetch next step's xg
            int rb = (t + 1) * 16 + bblk;
#pragma unroll
            for (int q = 0; q < 4; q++)
                xn[q] = xg8[((size_t)rb * 64 + (q * 16 + w)) * 64 + l];
        }
        const short* hc = hb + cur * 4096;
        const short* cc = cb + cur * 4096;
        // cs = tanh(c @ Wd + bd)
        f32x4 csacc = {0.f, 0.f, 0.f, 0.f};
#pragma unroll
        for (int kk = 0; kk < 8; kk++) {
            bf16x8 cf = *(const bf16x8*)&cc[col * 256 + ((kk * 32 + lgrp * 8) ^ ((col & 7) << 3))];
            csacc = __builtin_amdgcn_mfma_f32_16x16x32_bf16(cf, wd[kk], csacc, 0, 0, 0);
        }
        // g = xg + h @ Wh
        f32x4 gacc[4];
#pragma unroll
        for (int q = 0; q < 4; q++) {
            uint2 v = xc[q];
            gacc[q][0] = bfbits_lo(v.x);
            gacc[q][1] = bfbits_hi(v.x);
            gacc[q][2] = bfbits_lo(v.y);
            gacc[q][3] = bfbits_hi(v.y);
        }
#pragma unroll
        for (int kk = 0; kk < 8; kk++) {
            bf16x8 hf = *(const bf16x8*)&hc[col * 256 + ((kk * 32 + lgrp * 8) ^ ((col & 7) << 3))];
#pragma unroll
            for (int q = 0; q < 4; q++)
                gacc[q] = __builtin_amdgcn_mfma_f32_16x16x32_bf16(
                    hf, Whp8[((size_t)(q * 16 + w) * 8 + kk) * 64 + l], gacc[q], 0, 0, 0);
        }
        short* hx = hb + (cur ^ 1) * 4096;
        short* cx = cb + (cur ^ 1) * 4096;
#pragma unroll
        for (int r = 0; r < 4; r++) {
            int row = lgrp * 4 + r;
            float dec = decs[t * 17 + row];
            float cs = tanhf_(csacc[r] + bdv);
            float cadj = creg[r] - cs + cs * dec;
            float iv = sigmoidf_(gacc[0][r]);
            float fv = sigmoidf_(gacc[1][r]);
            float ov = sigmoidf_(gacc[2][r]);
            float cd = tanhf_(gacc[3][r]);
            float cn = fv * cadj + iv * cd;
            float hn = ov * tanhf_(cn);
            creg[r] = cn;
            int sw = n ^ ((row & 7) << 3);
            unsigned short hnb = f2bf(hn);
            hx[row * 256 + sw] = (short)hnb;
            cx[row * 256 + sw] = (short)f2bf(cn);
            size_t yi = ((size_t)(b0 + row) * S_ + tg) * H_ + n;
            if constexpr (ISL0) {
                ((unsigned short*)yout)[yi] = hnb;
                if (w == 15 && col == 15)
                    dec_out[(size_t)(b0 + row) * S_ + tg] = 1.f / __logf(2.718281828459045f + hn);
            } else {
                ((float*)yout)[yi] = hn;
            }
            if (t == CHUNK - 1) {
                h_state[(size_t)(b0 + row) * H_ + n] = hnb;
                c_state[(size_t)(b0 + row) * H_ + n] = cn;
            }
        }
#pragma unroll
        for (int q = 0; q < 4; q++) xc[q] = xn[q];
        cur ^= 1;
        __syncthreads();
    }
}

// fused dual-layer scan: blocks 0..15 -> layer0 chunk c0, blocks 16..31 -> layer1 chunk c1
__global__ __launch_bounds__(1024, 4) void rec_fused(
    const unsigned short* __restrict__ xgpA, const unsigned short* __restrict__ Whp0,
    const unsigned short* __restrict__ Wdp0, const float* __restrict__ bd0,
    const float* __restrict__ dec0, unsigned short* __restrict__ y0bf,
    float* __restrict__ dec1, unsigned short* __restrict__ hs0, float* __restrict__ cs0,
    const unsigned short* __restrict__ xgpB, const unsigned short* __restrict__ Whp1,
    const unsigned short* __restrict__ Wdp1, const float* __restrict__ bd1,
    float* __restrict__ y1, unsigned short* __restrict__ hs1, float* __restrict__ cs1,
    int c0, int c1) {
    extern __shared__ char smem[];
    int lay = blockIdx.x >> 4, bblk = blockIdx.x & 15;
    if (lay == 0) {
        if (c0 < 0) return;
        rec_run<true>(xgpA, (const bf16x8*)Whp0, (const bf16x8*)Wdp0, bd0, dec0, y0bf, dec1,
                      hs0, cs0, c0, bblk, smem);
    } else {
        if (c1 < 0) return;
        rec_run<false>(xgpB, (const bf16x8*)Whp1, (const bf16x8*)Wdp1, bd1, dec1, y1, nullptr,
                       hs1, cs1, c1, bblk, smem);
    }
}

__global__ void copy_tail(const unsigned short* __restrict__ h0, const float* __restrict__ c0,
                          const unsigned short* __restrict__ h1, const float* __restrict__ c1,
                          float* __restrict__ out) {
    int i = blockIdx.x * 256 + threadIdx.x;
    if (i >= 4 * 65536) return;
    int which = i >> 16, j = i & 65535;
    float v = which == 0 ? bf2f(h0[j]) : which == 1 ? c0[j] : which == 2 ? bf2f(h1[j]) : c1[j];
    out[i] = v;
}

extern "C" void kernel_launch(void* const* d_in, const int* in_sizes, int n_in, void* d_out,
                              int out_size, void* d_ws, size_t ws_size, hipStream_t stream) {
    (void)in_sizes; (void)n_in; (void)out_size; (void)ws_size;
    const float* x   = (const float*)d_in[0];
    const float* Wx0 = (const float*)d_in[1];
    const float* Wh0 = (const float*)d_in[2];
    const float* b0  = (const float*)d_in[3];
    const float* Wd0 = (const float*)d_in[4];
    const float* bd0 = (const float*)d_in[5];
    const float* Wx1 = (const float*)d_in[6];
    const float* Wh1 = (const float*)d_in[7];
    const float* b1  = (const float*)d_in[8];
    const float* Wd1 = (const float*)d_in[9];
    const float* bd1 = (const float*)d_in[10];

    char* ws = (char*)d_ws;
    size_t off = 0;
    auto take = [&](size_t bytes) { void* p = ws + off; off += (bytes + 255) & ~(size_t)255; return p; };
    unsigned short* wxp0 = (unsigned short*)take(524288);
    unsigned short* whp0 = (unsigned short*)take(524288);
    unsigned short* wdp0 = (unsigned short*)take(131072);
    unsigned short* wxp1 = (unsigned short*)take(524288);
    unsigned short* whp1 = (unsigned short*)take(524288);
    unsigned short* wdp1 = (unsigned short*)take(131072);
    float* dec0 = (float*)take(524288);
    float* dec1 = (float*)take(524288);
    unsigned short* hs0 = (unsigned short*)take(131072);
    float* cs0 = (float*)take(262144);
    unsigned short* hs1 = (unsigned short*)take(131072);
    float* cs1 = (float*)take(262144);
    unsigned short* y0bf = (unsigned short*)take(67108864);
    unsigned short* xgpA = (unsigned short*)take(16777216);
    unsigned short* xgpB = (unsigned short*)take(16777216);

    prep_w<<<128, 256, 0, stream>>>(Wx0, wxp0, 64);
    prep_w<<<128, 256, 0, stream>>>(Wh0, whp0, 64);
    prep_w<<<32, 256, 0, stream>>>(Wd0, wdp0, 16);
    prep_w<<<128, 256, 0, stream>>>(Wx1, wxp1, 64);
    prep_w<<<128, 256, 0, stream>>>(Wh1, whp1, 64);
    prep_w<<<32, 256, 0, stream>>>(Wd1, wdp1, 16);
    prep_decay<<<512, 256, 0, stream>>>(x, dec0, B_ * S_);

    float* y1 = (float*)d_out;
    const size_t smem_rec = 4 * 4096 * 2 + CHUNK * 17 * 4;  // 34.9 KB
    for (int s = 0; s <= NCHUNK; ++s) {
        int c0 = (s < NCHUNK) ? s : -1;
        int c1 = (s >= 1) ? s - 1 : -1;
        gemm_dual<<<dim3(64, 8, 2), 256, 65536, stream>>>(x, y0bf, wxp0, b0, wxp1, b1,
                                                          xgpA, xgpB, c0, c1);
        rec_fused<<<32, 1024, smem_rec, stream>>>(xgpA, whp0, wdp0, bd0, dec0, y0bf, dec1,
                                                  hs0, cs0, xgpB, whp1, wdp1, bd1, y1,
                                                  hs1, cs1, c0, c1);
    }
    copy_tail<<<1024, 256, 0, stream>>>(hs0, cs0, hs1, cs1, y1 + (size_t)B_ * S_ * H_);
}

// Round 3
// 9128.735 us; speedup vs baseline: 1.6500x; 1.0169x over previous
//
#include <hip/hip_runtime.h>
#include <stdint.h>

#define B_ 256
#define S_ 512
#define H_ 256
#define G_ 1024
#define CHUNK 32
#define NCHUNK (S_ / CHUNK)

typedef __attribute__((ext_vector_type(8))) short bf16x8;
typedef __attribute__((ext_vector_type(4))) float f32x4;

__device__ __forceinline__ unsigned short f2bf(float f) {
    unsigned u = __builtin_bit_cast(unsigned, f);
    unsigned r = u + 0x7fffu + ((u >> 16) & 1u);
    return (unsigned short)(r >> 16);
}
__device__ __forceinline__ float bf2f(unsigned short v) {
    return __builtin_bit_cast(float, (unsigned)v << 16);
}
__device__ __forceinline__ float bfbits_lo(unsigned v) {
    return __builtin_bit_cast(float, (unsigned)(v << 16));
}
__device__ __forceinline__ float bfbits_hi(unsigned v) {
    return __builtin_bit_cast(float, v & 0xffff0000u);
}
__device__ __forceinline__ float sigmoidf_(float x) { return 1.f / (1.f + __expf(-x)); }
__device__ __forceinline__ float tanhf_(float x) { return 2.f / (1.f + __expf(-2.f * x)) - 1.f; }

// ---------------- prep: weights -> fragment-major bf16 ----------------
// Wp[nt][kk][lane][i] = W[k][n], k = kk*32 + (lane>>4)*8 + i, n = nt*16 + (lane&15)
__global__ void prep_w(const float* __restrict__ W, unsigned short* __restrict__ Wp, int NT) {
    int tid = blockIdx.x * 256 + threadIdx.x;
    int total = NT * 8 * 64;
    if (tid >= total) return;
    int l = tid & 63, kk = (tid >> 6) & 7, nt = tid >> 9;
    int n = nt * 16 + (l & 15);
    int k0 = kk * 32 + (l >> 4) * 8;
    int N = NT * 16;
    unsigned short v[8];
#pragma unroll
    for (int i = 0; i < 8; i++) v[i] = f2bf(W[(size_t)(k0 + i) * N + n]);
    uint4 o;
    o.x = (unsigned)v[0] | ((unsigned)v[1] << 16);
    o.y = (unsigned)v[2] | ((unsigned)v[3] << 16);
    o.z = (unsigned)v[4] | ((unsigned)v[5] << 16);
    o.w = (unsigned)v[6] | ((unsigned)v[7] << 16);
    *(uint4*)(Wp + (size_t)tid * 8) = o;
}

__global__ void prep_decay(const float* __restrict__ x, float* __restrict__ dec, int n) {
    int i = blockIdx.x * 256 + threadIdx.x;
    if (i < n) dec[i] = 1.f / __logf(2.718281828459045f + x[(size_t)i * H_ + (H_ - 1)]);
}

// ---------------- xg GEMM body ----------------
// Output layout (fragment-major): xgp[rowblk][qg 0..63][lane][4 bf16], rowblk = t_local*16 + b/16
template <bool SRCF32>
__device__ void gemm_body(const void* __restrict__ src, const unsigned short* __restrict__ Wp,
                          const float* __restrict__ bias, unsigned short* __restrict__ xgp,
                          int chunk, short* Albs) {
    const int tid = threadIdx.x;
    const int bx = blockIdx.x;  // 0..63 M-tile (128 rows)
    const int by = blockIdx.y;  // 0..7  N-block
    const int r0 = bx * 128;
    const int t_loc = r0 >> 8;
    const int b0 = r0 & 255;
    const int sg = chunk * CHUNK + t_loc;
    {
        const int m = tid >> 1, kh = tid & 1;
        const size_t rowbase = ((size_t)(b0 + m) * S_ + sg) * H_ + kh * 128;
        if constexpr (SRCF32) {
            const float* p = (const float*)src + rowbase;
#pragma unroll
            for (int jo = 0; jo < 16; jo++) {
                int k = kh * 128 + jo * 8;
                float4 a = *(const float4*)(p + jo * 8);
                float4 b = *(const float4*)(p + jo * 8 + 4);
                int slot = ((m >> 4) * 8 + (k >> 5)) * 64 + ((m & 15) | (((k >> 3) & 3) << 4));
                uint4 o;
                o.x = (unsigned)f2bf(a.x) | ((unsigned)f2bf(a.y) << 16);
                o.y = (unsigned)f2bf(a.z) | ((unsigned)f2bf(a.w) << 16);
                o.z = (unsigned)f2bf(b.x) | ((unsigned)f2bf(b.y) << 16);
                o.w = (unsigned)f2bf(b.z) | ((unsigned)f2bf(b.w) << 16);
                *(uint4*)&Albs[slot * 8] = o;
            }
        } else {
            const unsigned short* p = (const unsigned short*)src + rowbase;
#pragma unroll
            for (int jo = 0; jo < 16; jo++) {
                int k = kh * 128 + jo * 8;
                uint4 o = *(const uint4*)(p + jo * 8);
                int slot = ((m >> 4) * 8 + (k >> 5)) * 64 + ((m & 15) | (((k >> 3) & 3) << 4));
                *(uint4*)&Albs[slot * 8] = o;
            }
        }
    }
    __syncthreads();
    const int w = tid >> 6, l = tid & 63;
    const int wm = w >> 1, wn = w & 1;
    const int col = l & 15;
    float bv[4];
#pragma unroll
    for (int q = 0; q < 4; q++) bv[q] = bias[(by * 8 + wn * 4 + q) * 16 + col];
    f32x4 acc[4][4];
#pragma unroll
    for (int mi = 0; mi < 4; mi++)
#pragma unroll
        for (int q = 0; q < 4; q++) {
            acc[mi][q][0] = bv[q]; acc[mi][q][1] = bv[q];
            acc[mi][q][2] = bv[q]; acc[mi][q][3] = bv[q];
        }
    const bf16x8* Wp8 = (const bf16x8*)Wp;
#pragma unroll
    for (int kk = 0; kk < 8; kk++) {
        bf16x8 af[4], bfr[4];
#pragma unroll
        for (int mi = 0; mi < 4; mi++)
            af[mi] = *(const bf16x8*)&Albs[(((wm * 4 + mi) * 8 + kk) * 64 + l) * 8];
#pragma unroll
        for (int q = 0; q < 4; q++)
            bfr[q] = Wp8[((size_t)(by * 8 + wn * 4 + q) * 8 + kk) * 64 + l];
#pragma unroll
        for (int mi = 0; mi < 4; mi++)
#pragma unroll
            for (int q = 0; q < 4; q++)
                acc[mi][q] = __builtin_amdgcn_mfma_f32_16x16x32_bf16(af[mi], bfr[q], acc[mi][q], 0, 0, 0);
    }
    const int rblk0 = r0 >> 4;
#pragma unroll
    for (int mi = 0; mi < 4; mi++) {
        int rowblk = rblk0 + wm * 4 + mi;
#pragma unroll
        for (int q = 0; q < 4; q++) {
            int qg = by * 8 + wn * 4 + q;
            uint2 o;
            o.x = (unsigned)f2bf(acc[mi][q][0]) | ((unsigned)f2bf(acc[mi][q][1]) << 16);
            o.y = (unsigned)f2bf(acc[mi][q][2]) | ((unsigned)f2bf(acc[mi][q][3]) << 16);
            *(uint2*)&xgp[(((size_t)rowblk * 64 + qg) * 64 + l) * 4] = o;
        }
    }
}

// dual-layer GEMM: z=0 -> layer0 chunk c0 (f32 src x), z=1 -> layer1 chunk c1 (bf16 src y0)
__global__ __launch_bounds__(256) void gemm_dual(const float* __restrict__ x,
                                                 const unsigned short* __restrict__ y0bf,
                                                 const unsigned short* __restrict__ Wp0,
                                                 const float* __restrict__ bias0,
                                                 const unsigned short* __restrict__ Wp1,
                                                 const float* __restrict__ bias1,
                                                 unsigned short* __restrict__ xgpA,
                                                 unsigned short* __restrict__ xgpB, int c0, int c1) {
    extern __shared__ short Albs[];  // 64 KB
    if (blockIdx.z == 0) {
        if (c0 < 0) return;
        gemm_body<true>(x, Wp0, bias0, xgpA, c0, Albs);
    } else {
        if (c1 < 0) return;
        gemm_body<false>(y0bf, Wp1, bias1, xgpB, c1, Albs);
    }
}

// ---------------- recurrent scan: 16 WGs/layer x 512 threads (8 waves) ----------------
// Wave w owns column blocks {2w, 2w+1}; for each: 4 gate n-tiles (q*16+cb) + 1 Wd tile.
// WG = 16 batch rows. Wd register-resident; Wh fragments double-buffered (step-invariant
// rotation: at kk we prefetch (kk+1)&7, so kk=7 prefetches next step's kk=0 batch).
template <bool ISL0>
__device__ void rec_run(const unsigned short* __restrict__ xgp, const bf16x8* __restrict__ Whp8,
                        const bf16x8* __restrict__ Wdp8, const float* __restrict__ bd,
                        const float* __restrict__ dec_in, void* __restrict__ yout,
                        float* __restrict__ dec_out, unsigned short* __restrict__ h_state,
                        float* __restrict__ c_state, int chunk, int bblk, char* smem) {
    short* hb = (short*)smem;                     // [2][16][256]
    short* cbuf = (short*)(smem + 2 * 4096 * 2);  // [2][16][256]
    float* decs = (float*)(smem + 4 * 4096 * 2);  // [CHUNK][17]
    const int tid = threadIdx.x;  // 0..511
    const int w = tid >> 6, l = tid & 63;
    const int lgrp = l >> 4, col = l & 15;
    const int b0 = bblk * 16;
    const float bdv[2] = {bd[(2 * w) * 16 + col], bd[(2 * w + 1) * 16 + col]};

    {  // stage decay for this chunk, coalesced-ish
        int row = tid >> 5, t = tid & (CHUNK - 1);
        decs[t * 17 + row] = dec_in[(size_t)(b0 + row) * S_ + chunk * CHUNK + t];
    }
    // Wd tiles resident in registers for the whole chunk (2 tiles x 8 frags = 64 VGPR)
    bf16x8 wd[2][8];
#pragma unroll
    for (int j = 0; j < 2; j++)
#pragma unroll
        for (int kk = 0; kk < 8; kk++) wd[j][kk] = Wdp8[((size_t)(2 * w + j) * 8 + kk) * 64 + l];

    float creg[2][4];
    if (chunk == 0) {
#pragma unroll
        for (int j = 0; j < 2; j++)
#pragma unroll
            for (int r = 0; r < 4; r++) creg[j][r] = 0.f;
        for (int i = tid; i < 4096; i += 512) { hb[i] = 0; cbuf[i] = 0; }
    } else {
#pragma unroll
        for (int j = 0; j < 2; j++)
#pragma unroll
            for (int r = 0; r < 4; r++) {
                int row = lgrp * 4 + r;
                int n = (2 * w + j) * 16 + col;
                float cv = c_state[(size_t)(b0 + row) * H_ + n];
                creg[j][r] = cv;
                unsigned short hv = h_state[(size_t)(b0 + row) * H_ + n];
                int sw = n ^ ((row & 7) << 3);
                hb[row * 256 + sw] = (short)hv;
                cbuf[row * 256 + sw] = (short)f2bf(cv);
            }
    }
    __syncthreads();

    const uint2* xg8 = (const uint2*)xgp;
    uint2 xc[2][4], xn[2][4];
#pragma unroll
    for (int j = 0; j < 2; j++)
#pragma unroll
        for (int q = 0; q < 4; q++)
            xc[j][q] = xg8[((size_t)(0 * 16 + bblk) * 64 + (q * 16 + 2 * w + j)) * 64 + l];
    // preload Wh kk=0 fragment batch (step-invariant)
    bf16x8 whb[2][2][4];  // [buf][j][q]
#pragma unroll
    for (int j = 0; j < 2; j++)
#pragma unroll
        for (int q = 0; q < 4; q++)
            whb[0][j][q] = Whp8[((size_t)(q * 16 + 2 * w + j) * 8 + 0) * 64 + l];
    int cur = 0;

#pragma unroll 1
    for (int t = 0; t < CHUNK; ++t) {
        const int tg = chunk * CHUNK + t;
        if (t + 1 < CHUNK) {  // prefetch next step's xg
            int rb = (t + 1) * 16 + bblk;
#pragma unroll
            for (int j = 0; j < 2; j++)
#pragma unroll
                for (int q = 0; q < 4; q++)
                    xn[j][q] = xg8[((size_t)rb * 64 + (q * 16 + 2 * w + j)) * 64 + l];
        }
        const short* hc = hb + cur * 4096;
        const short* cc = cbuf + cur * 4096;
        f32x4 csacc[2];
        f32x4 gacc[2][4];
#pragma unroll
        for (int j = 0; j < 2; j++) {
            csacc[j][0] = 0.f; csacc[j][1] = 0.f; csacc[j][2] = 0.f; csacc[j][3] = 0.f;
#pragma unroll
            for (int q = 0; q < 4; q++) {
                uint2 v = xc[j][q];
                gacc[j][q][0] = bfbits_lo(v.x);
                gacc[j][q][1] = bfbits_hi(v.x);
                gacc[j][q][2] = bfbits_lo(v.y);
                gacc[j][q][3] = bfbits_hi(v.y);
            }
        }
#pragma unroll
        for (int kk = 0; kk < 8; kk++) {
            const int nb = (kk + 1) & 1, cb_ = kk & 1;
            const int kkn = (kk + 1) & 7;  // kk=7 prefetches next step's kk=0
#pragma unroll
            for (int j = 0; j < 2; j++)
#pragma unroll
                for (int q = 0; q < 4; q++)
                    whb[nb][j][q] = Whp8[((size_t)(q * 16 + 2 * w + j) * 8 + kkn) * 64 + l];
            bf16x8 hf = *(const bf16x8*)&hc[col * 256 + ((kk * 32 + lgrp * 8) ^ ((col & 7) << 3))];
            bf16x8 cf = *(const bf16x8*)&cc[col * 256 + ((kk * 32 + lgrp * 8) ^ ((col & 7) << 3))];
#pragma unroll
            for (int j = 0; j < 2; j++)
                csacc[j] = __builtin_amdgcn_mfma_f32_16x16x32_bf16(cf, wd[j][kk], csacc[j], 0, 0, 0);
#pragma unroll
            for (int j = 0; j < 2; j++)
#pragma unroll
                for (int q = 0; q < 4; q++)
                    gacc[j][q] = __builtin_amdgcn_mfma_f32_16x16x32_bf16(hf, whb[cb_][j][q],
                                                                         gacc[j][q], 0, 0, 0);
        }
        short* hx = hb + (cur ^ 1) * 4096;
        short* cx = cbuf + (cur ^ 1) * 4096;
#pragma unroll
        for (int j = 0; j < 2; j++) {
            const int n = (2 * w + j) * 16 + col;
#pragma unroll
            for (int r = 0; r < 4; r++) {
                int row = lgrp * 4 + r;
                float dec = decs[t * 17 + row];
                float cs = tanhf_(csacc[j][r] + bdv[j]);
                float cadj = creg[j][r] - cs + cs * dec;
                float iv = sigmoidf_(gacc[j][0][r]);
                float fv = sigmoidf_(gacc[j][1][r]);
                float ov = sigmoidf_(gacc[j][2][r]);
                float cd = tanhf_(gacc[j][3][r]);
                float cn = fv * cadj + iv * cd;
                float hn = ov * tanhf_(cn);
                creg[j][r] = cn;
                int sw = n ^ ((row & 7) << 3);
                unsigned short hnb = f2bf(hn);
                hx[row * 256 + sw] = (short)hnb;
                cx[row * 256 + sw] = (short)f2bf(cn);
                size_t yi = ((size_t)(b0 + row) * S_ + tg) * H_ + n;
                if constexpr (ISL0) {
                    ((unsigned short*)yout)[yi] = hnb;
                    if (w == 7 && j == 1 && col == 15)
                        dec_out[(size_t)(b0 + row) * S_ + tg] =
                            1.f / __logf(2.718281828459045f + hn);
                } else {
                    ((float*)yout)[yi] = hn;
                }
                if (t == CHUNK - 1) {
                    h_state[(size_t)(b0 + row) * H_ + n] = hnb;
                    c_state[(size_t)(b0 + row) * H_ + n] = cn;
                }
            }
        }
#pragma unroll
        for (int j = 0; j < 2; j++)
#pragma unroll
            for (int q = 0; q < 4; q++) xc[j][q] = xn[j][q];
        cur ^= 1;
        __syncthreads();
    }
}

// fused dual-layer scan: blocks 0..15 -> layer0 chunk c0, blocks 16..31 -> layer1 chunk c1
__global__ __launch_bounds__(512, 2) void rec_fused(
    const unsigned short* __restrict__ xgpA, const unsigned short* __restrict__ Whp0,
    const unsigned short* __restrict__ Wdp0, const float* __restrict__ bd0,
    const float* __restrict__ dec0, unsigned short* __restrict__ y0bf,
    float* __restrict__ dec1, unsigned short* __restrict__ hs0, float* __restrict__ cs0,
    const unsigned short* __restrict__ xgpB, const unsigned short* __restrict__ Whp1,
    const unsigned short* __restrict__ Wdp1, const float* __restrict__ bd1,
    float* __restrict__ y1, unsigned short* __restrict__ hs1, float* __restrict__ cs1,
    int c0, int c1) {
    extern __shared__ char smem[];
    int lay = blockIdx.x >> 4, bblk = blockIdx.x & 15;
    if (lay == 0) {
        if (c0 < 0) return;
        rec_run<true>(xgpA, (const bf16x8*)Whp0, (const bf16x8*)Wdp0, bd0, dec0, y0bf, dec1,
                      hs0, cs0, c0, bblk, smem);
    } else {
        if (c1 < 0) return;
        rec_run<false>(xgpB, (const bf16x8*)Whp1, (const bf16x8*)Wdp1, bd1, dec1, y1, nullptr,
                       hs1, cs1, c1, bblk, smem);
    }
}

__global__ void copy_tail(const unsigned short* __restrict__ h0, const float* __restrict__ c0,
                          const unsigned short* __restrict__ h1, const float* __restrict__ c1,
                          float* __restrict__ out) {
    int i = blockIdx.x * 256 + threadIdx.x;
    if (i >= 4 * 65536) return;
    int which = i >> 16, j = i & 65535;
    float v = which == 0 ? bf2f(h0[j]) : which == 1 ? c0[j] : which == 2 ? bf2f(h1[j]) : c1[j];
    out[i] = v;
}

extern "C" void kernel_launch(void* const* d_in, const int* in_sizes, int n_in, void* d_out,
                              int out_size, void* d_ws, size_t ws_size, hipStream_t stream) {
    (void)in_sizes; (void)n_in; (void)out_size; (void)ws_size;
    const float* x   = (const float*)d_in[0];
    const float* Wx0 = (const float*)d_in[1];
    const float* Wh0 = (const float*)d_in[2];
    const float* b0  = (const float*)d_in[3];
    const float* Wd0 = (const float*)d_in[4];
    const float* bd0 = (const float*)d_in[5];
    const float* Wx1 = (const float*)d_in[6];
    const float* Wh1 = (const float*)d_in[7];
    const float* b1  = (const float*)d_in[8];
    const float* Wd1 = (const float*)d_in[9];
    const float* bd1 = (const float*)d_in[10];

    char* ws = (char*)d_ws;
    size_t off = 0;
    auto take = [&](size_t bytes) { void* p = ws + off; off += (bytes + 255) & ~(size_t)255; return p; };
    unsigned short* wxp0 = (unsigned short*)take(524288);
    unsigned short* whp0 = (unsigned short*)take(524288);
    unsigned short* wdp0 = (unsigned short*)take(131072);
    unsigned short* wxp1 = (unsigned short*)take(524288);
    unsigned short* whp1 = (unsigned short*)take(524288);
    unsigned short* wdp1 = (unsigned short*)take(131072);
    float* dec0 = (float*)take(524288);
    float* dec1 = (float*)take(524288);
    unsigned short* hs0 = (unsigned short*)take(131072);
    float* cs0 = (float*)take(262144);
    unsigned short* hs1 = (unsigned short*)take(131072);
    float* cs1 = (float*)take(262144);
    unsigned short* y0bf = (unsigned short*)take(67108864);
    unsigned short* xgpA = (unsigned short*)take(16777216);
    unsigned short* xgpB = (unsigned short*)take(16777216);

    prep_w<<<128, 256, 0, stream>>>(Wx0, wxp0, 64);
    prep_w<<<128, 256, 0, stream>>>(Wh0, whp0, 64);
    prep_w<<<32, 256, 0, stream>>>(Wd0, wdp0, 16);
    prep_w<<<128, 256, 0, stream>>>(Wx1, wxp1, 64);
    prep_w<<<128, 256, 0, stream>>>(Wh1, whp1, 64);
    prep_w<<<32, 256, 0, stream>>>(Wd1, wdp1, 16);
    prep_decay<<<512, 256, 0, stream>>>(x, dec0, B_ * S_);

    float* y1 = (float*)d_out;
    const size_t smem_rec = 4 * 4096 * 2 + CHUNK * 17 * 4;  // 34.9 KB
    for (int s = 0; s <= NCHUNK; ++s) {
        int c0 = (s < NCHUNK) ? s : -1;
        int c1 = (s >= 1) ? s - 1 : -1;
        gemm_dual<<<dim3(64, 8, 2), 256, 65536, stream>>>(x, y0bf, wxp0, b0, wxp1, b1,
                                                          xgpA, xgpB, c0, c1);
        rec_fused<<<32, 512, smem_rec, stream>>>(xgpA, whp0, wdp0, bd0, dec0, y0bf, dec1,
                                                 hs0, cs0, xgpB, whp1, wdp1, bd1, y1,
                                                 hs1, cs1, c0, c1);
    }
    copy_tail<<<1024, 256, 0, stream>>>(hs0, cs0, hs1, cs1, y1 + (size_t)B_ * S_ * H_);
}